// Round 9
// baseline (250.207 us; speedup 1.0000x reference)
//
#include <hip/hip_runtime.h>
#include <hip/hip_bf16.h>
#include <stdint.h>

#define N_NODES 100000
#define N_EDGES 1600000
#define DIM     128
#define ALPHA   0.01f
#define BN_EPS  1e-5f
#define NBUCK   3125          // 100000/32 buckets of 32 dst nodes (exact)
#define NBLK_P  256           // partition blocks (full chip for p3)
#define EPB     6250          // edges per partition block (256*6250 = 1.6M exact)
#define SRT_CAP 1536          // LDS sort capacity (>= BCKT_CAP)
#define BCKT_CAP 1024         // static per-bucket slot in tmp (avg 512, sigma ~23: +22s safe)
#define GEMM_GRID 3125        // 100000/32 rows per block (exact)

typedef __bf16 bf16x8 __attribute__((ext_vector_type(8)));
typedef float  f32x4  __attribute__((ext_vector_type(4)));
typedef float  f32x2  __attribute__((ext_vector_type(2)));

#if defined(__has_builtin)
#if __has_builtin(__builtin_amdgcn_cvt_pk_fp8_f32) && __has_builtin(__builtin_amdgcn_cvt_pk_f32_fp8)
#define USE_FP8_BUILTIN 1
#endif
#endif

// ---- workspace layout (bytes) ----
static const size_t OFF_SUM   = 512;         // 8 replicas x (128 gsum + 128 gsumsq) f32 = 8 KB
static const size_t OFF_BT    = 14592;       // 3125 ints: per-bucket edge counts
static const size_t OFF_BFRAG = 6432768;     // 64 KiB (end 6498304)
static const size_t OFF_AMEAN = 6498304;     // 100000x128 bf16 (end 32098304)
static const size_t OFF_X8    = 32098304;    // 100000x128 fp8 (end 44898304)
static const size_t OFF_H     = 44898304;    // 100000x128 bf16 (end 70498304)
// H region is dead until gemm -> overlay the transient buffers (stream-ordered):
static const size_t OFF_GHIST = OFF_H;                    // 256*3125 ints = 3.2 MB
static const size_t OFF_SOFFT = OFF_H + 4194304;          // 256*3125 ints = 3.2 MB
static const size_t OFF_TMP2  = OFF_H + 8388608;          // 3125*1024 u32 = 12.8 MB (ends OFF_H+21.2MB < +25.6MB)
static const size_t OFF_XB    = 70498304;    // 100000x128 bf16 x-copy (end 96098304)

__device__ __forceinline__ float bf2f(unsigned short h) {
    return __uint_as_float(((unsigned int)h) << 16);
}
__device__ __forceinline__ float bflo(unsigned int w) {
    return __uint_as_float(w << 16);
}
__device__ __forceinline__ float bfhi(unsigned int w) {
    return __uint_as_float(w & 0xffff0000u);
}
__device__ __forceinline__ unsigned short f2bf(float f) {
    unsigned int u = __float_as_uint(f);
    u = u + 0x7fffu + ((u >> 16) & 1u);   // round-to-nearest-even
    return (unsigned short)(u >> 16);
}
__device__ __forceinline__ unsigned int pack2(float a, float b) {
    return (unsigned int)f2bf(a) | ((unsigned int)f2bf(b) << 16);
}
__device__ __forceinline__ float loadS(const void* p, int i, int isf32) {
    return isf32 ? ((const float*)p)[i] : bf2f(((const unsigned short*)p)[i]);
}
__device__ __forceinline__ int edge_at(const void* e, long long i, int idx64) {
    return idx64 ? (int)((const long long*)e)[i] : ((const int*)e)[i];
}
// per-bucket chunk position of partition block k: group by (k&7) = likely XCD,
// so chunks sharing cache lines come from ONE XCD's L2 and can merge.
__device__ __forceinline__ int blkpos(int k) { return ((k & 7) << 5) | (k >> 3); }
// inverse: source block for chunk position p  (posblk(c*32+i) == i*8+c)
__device__ __forceinline__ int posblk(int p) { return ((p & 31) << 3) | (p >> 5); }

// CK-style global->LDS direct copy, 16B per lane (dest must be linear in lane order)
__device__ __forceinline__ void gload_lds16(const void* g, void* l) {
    __builtin_amdgcn_global_load_lds(
        reinterpret_cast<const __attribute__((address_space(1))) unsigned int*>(
            reinterpret_cast<uintptr_t>(g)),
        reinterpret_cast<__attribute__((address_space(3))) unsigned int*>(
            reinterpret_cast<uintptr_t>(l)),
        16, 0, 0);
}

// ---- fp8 e4m3 encode/decode ----
#ifndef USE_FP8_BUILTIN
__device__ __forceinline__ unsigned int enc_fp8_1(float f) {
    unsigned int u = __float_as_uint(f);
    unsigned int s = (u >> 24) & 0x80u;
    unsigned int au = u & 0x7fffffffu;
    if (au >= 0x43E00000u) return s | 0x7Eu;               // clamp to 448
    if (au < 0x3C800000u) {                                 // subnormal / zero
        int m = (int)rintf(__uint_as_float(au) * 512.0f);
        return s | (unsigned int)m;
    }
    unsigned int r = au + 0x7FFFFu + ((au >> 20) & 1u);     // RNE to 3 mantissa bits
    unsigned int e = (r >> 23) & 0xffu;
    unsigned int m3 = (r >> 20) & 7u;
    return s | ((e - 120u) << 3) | m3;
}
#endif
__device__ __forceinline__ unsigned int enc4(float f0, float f1, float f2, float f3) {
#ifdef USE_FP8_BUILTIN
    int r = __builtin_amdgcn_cvt_pk_fp8_f32(f0, f1, 0, false);
    r = __builtin_amdgcn_cvt_pk_fp8_f32(f2, f3, r, true);
    return (unsigned int)r;
#else
    return enc_fp8_1(f0) | (enc_fp8_1(f1) << 8) | (enc_fp8_1(f2) << 16) | (enc_fp8_1(f3) << 24);
#endif
}
__device__ __forceinline__ void dec4(unsigned int w, float* o) {
#ifdef USE_FP8_BUILTIN
    f32x2 a = __builtin_amdgcn_cvt_pk_f32_fp8(w, false);
    f32x2 b = __builtin_amdgcn_cvt_pk_f32_fp8(w, true);
    o[0] = a[0]; o[1] = a[1]; o[2] = b[0]; o[3] = b[1];
#else
    #pragma unroll
    for (int j = 0; j < 4; j++) {
        unsigned int c = (w >> (8 * j)) & 0xffu;
        o[j] = __uint_as_float(((c & 0x80u) << 24) | ((c & 0x7fu) << 20)) * 0x1p120f;
    }
#endif
}

// ---- wave-uniform dtype detection ----
__device__ __forceinline__ int detect_idx64(const void* e) {
    const unsigned int* ew = (const unsigned int*)e;
    unsigned long long m = __ballot(ew[2 * (threadIdx.x & 63) + 1] != 0u);
    return (__popcll(m) < 8) ? 1 : 0;
}
__device__ __forceinline__ int detect_isf32(const void* x) {
    const unsigned int* xw = (const unsigned int*)x;
    unsigned int w = xw[threadIdx.x & 63];
    unsigned int e = (w >> 7) & 0xffu;
    bool bflike = (e >= 110u && e <= 140u) || ((w & 0xffffu) == 0u);
    unsigned long long m = __ballot(bflike);
    return (__popcll(m) > 32) ? 0 : 1;
}

// ---- k1: hist (blocks 0..255, block 0 zeros BN stat replicas) + x->fp8(+bf16) (3125 blocks)
//      + B-fragment swizzle prep (last 128 blocks) ----
__global__ __launch_bounds__(256) void k1_kernel(const void* edges, const void* x,
                                                 int* ghist, unsigned int* x8,
                                                 unsigned short* xb, float* gz,
                                                 const void* W_l, const void* W_r,
                                                 unsigned short* bfrag) {
    int tid = threadIdx.x;
    if (blockIdx.x < NBLK_P) {
        __shared__ int sh[NBUCK];
        int idx64 = detect_idx64(edges);
        int blk = blockIdx.x;
        if (blk == 0)
            for (int i = tid; i < 2048; i += 256) gz[i] = 0.f;   // 8 stat replicas
        for (int i = tid; i < NBUCK; i += 256) sh[i] = 0;
        __syncthreads();
        long long base = (long long)blk * EPB;
        for (int i = tid; i < EPB; i += 256) {
            int d = edge_at(edges, (long long)N_EDGES + base + i, idx64);
            atomicAdd(&sh[d >> 5], 1);
        }
        __syncthreads();
        for (int i = tid; i < NBUCK; i += 256) ghist[blk * NBUCK + i] = sh[i];
    } else if (blockIdx.x < NBLK_P + 3125) {
        int isf32 = detect_isf32(x);
        int gid = (blockIdx.x - NBLK_P) * 256 + tid;
        float f[16];
        if (!isf32) {
            const uint4* xv = (const uint4*)x;
            uint4 a = xv[gid * 2], b2 = xv[gid * 2 + 1];
            unsigned int w[8] = {a.x, a.y, a.z, a.w, b2.x, b2.y, b2.z, b2.w};
            #pragma unroll
            for (int i = 0; i < 8; i++) { f[2 * i] = bflo(w[i]); f[2 * i + 1] = bfhi(w[i]); }
        } else {
            const float4* xf = (const float4*)x;
            #pragma unroll
            for (int i = 0; i < 4; i++) {
                float4 v = xf[gid * 4 + i];
                f[4 * i] = v.x; f[4 * i + 1] = v.y; f[4 * i + 2] = v.z; f[4 * i + 3] = v.w;
            }
            // bf16 copy of x for the gemm A-side (halves its fetch, kills f2bf there)
            uint4 h1, h2;
            h1.x = pack2(f[0], f[1]);  h1.y = pack2(f[2], f[3]);
            h1.z = pack2(f[4], f[5]);  h1.w = pack2(f[6], f[7]);
            h2.x = pack2(f[8], f[9]);  h2.y = pack2(f[10], f[11]);
            h2.z = pack2(f[12], f[13]); h2.w = pack2(f[14], f[15]);
            ((uint4*)xb)[gid * 2]     = h1;
            ((uint4*)xb)[gid * 2 + 1] = h2;
        }
        uint4 o;
        o.x = enc4(f[0], f[1], f[2], f[3]);
        o.y = enc4(f[4], f[5], f[6], f[7]);
        o.z = enc4(f[8], f[9], f[10], f[11]);
        o.w = enc4(f[12], f[13], f[14], f[15]);
        *(uint4*)(x8 + gid * 4) = o;
    } else {
        // B-fragment swizzle: 128 blocks x 256 = 32768 elems
        int isf32 = detect_isf32(x);
        int g = (blockIdx.x - NBLK_P - 3125) * 256 + tid;
        int j    = g & 7;
        int lane = (g >> 3) & 63;
        int s    = (g >> 9) & 7;
        int tt   = (g >> 12) & 7;
        int n = tt * 16 + (lane & 15);
        int k = s * 32 + ((lane >> 4) & 3) * 8 + j;
        float v = (k < DIM) ? loadS(W_l, n * DIM + k, isf32)
                            : loadS(W_r, n * DIM + (k - DIM), isf32);
        bfrag[g] = f2bf(v);
    }
}

// ---- p2a: per-bucket scan, 8-way parallel over position-chunks ----
__global__ __launch_bounds__(512) void p2a_kernel(const int* __restrict__ ghist,
                                                  int* __restrict__ sOffT,
                                                  int* __restrict__ bT) {
    __shared__ int csum[8][64];
    int t = threadIdx.x;
    int c = t >> 6, bl = t & 63;
    int b = blockIdx.x * 64 + bl;
    int v[32]; int s = 0;
    if (b < NBUCK) {
        #pragma unroll
        for (int i = 0; i < 32; i++) { v[i] = ghist[(size_t)(i * 8 + c) * NBUCK + b]; s += v[i]; }
    }
    csum[c][bl] = s;
    __syncthreads();
    if (b < NBUCK) {
        int run = 0;
        for (int i = 0; i < c; i++) run += csum[i][bl];
        #pragma unroll
        for (int i = 0; i < 32; i++) { sOffT[(size_t)(c * 32 + i) * NBUCK + b] = run; run += v[i]; }
        if (c == 7) bT[b] = run;
    }
}

// ---- p3: scatter edges into STATIC bucket slots (bucket b occupies tmp[b<<10 ..]) ----
__global__ __launch_bounds__(1024) void p3_kernel(const void* edges, const int* __restrict__ sOffT,
                                                  unsigned int* __restrict__ tmp) {
    __shared__ int sbase[NBUCK];
    int idx64 = detect_idx64(edges);
    int blk = blockIdx.x, tid = threadIdx.x;
    int mypos = blkpos(blk);
    for (int i = tid; i < NBUCK; i += 1024)
        sbase[i] = (i << 10) + sOffT[(size_t)mypos * NBUCK + i];   // static slot + coalesced offset
    __syncthreads();
    long long base = (long long)blk * EPB;
    for (int i = tid; i < EPB; i += 1024) {
        long long e = base + i;
        int s = edge_at(edges, e, idx64);
        int d = edge_at(edges, (long long)N_EDGES + e, idx64);
        int bkt = d >> 5;
        int p = atomicAdd(&sbase[bkt], 1);
        if (p < ((bkt + 1) << 10))                      // slot-overflow clamp (+22 sigma, never fires)
            tmp[p] = ((unsigned int)(d & 31) << 17) | (unsigned int)s;
    }
}

// ---- aggregation: LDS counting sort, then oct-per-node gather (no cross-lane reduce) ----
__global__ __launch_bounds__(256) void agg_kernel(const unsigned int* x8, const unsigned int* tmp,
                                                  const int* __restrict__ bT, unsigned short* Amean) {
    __shared__ int s_cnt[32];
    __shared__ int s_beg[32];
    __shared__ int s_srt[SRT_CAP];
    int b = blockIdx.x, tid = threadIdx.x;
    int gb = b << 10;                       // static slot base
    int nE = min(bT[b], BCKT_CAP);
    if (tid < 32) s_cnt[tid] = 0;
    __syncthreads();
    for (int i = tid; i < nE; i += 256) atomicAdd(&s_cnt[tmp[gb + i] >> 17], 1);
    __syncthreads();
    if (tid < 32) {
        int v = s_cnt[tid];
        int sc = v;
        #pragma unroll
        for (int off = 1; off < 32; off <<= 1) {
            int u = __shfl_up(sc, off, 64);
            if (tid >= off) sc += u;
        }
        s_beg[tid] = sc - v;
        s_cnt[tid] = sc - v;    // reuse as write ptr
    }
    __syncthreads();
    for (int i = tid; i < nE; i += 256) {
        unsigned int w = tmp[gb + i];
        int p = atomicAdd(&s_cnt[w >> 17], 1);
        s_srt[p] = (int)(w & 0x1ffffu);
    }
    __syncthreads();
    // each 8-lane oct owns ONE node: no cross-lane reduction needed.
    int wv = tid >> 6, lane = tid & 63;
    int oct = lane >> 3, l8 = lane & 7;
    int nl = wv * 8 + oct;                  // node 0..31 within bucket
    int nb = s_beg[nl], ne2 = s_cnt[nl];
    const uint4* xv = (const uint4*)x8;     // fp8 row = 8 uint4
    float acc[16];
    #pragma unroll
    for (int i = 0; i < 16; i++) acc[i] = 0.f;
    for (int jj = nb; jj < ne2; jj += 4) {
        uint4 r[4]; float mk[4];
        #pragma unroll
        for (int u = 0; u < 4; u++) {
            int e = jj + u;
            int su = s_srt[(e < ne2) ? e : nb];   // LDS broadcast across the oct
            mk[u] = (e < ne2) ? 1.f : 0.f;
            r[u] = xv[(size_t)su * 8 + l8];
        }
        #pragma unroll
        for (int u = 0; u < 4; u++) {
            float f[4];
            dec4(r[u].x, f);
            acc[0] = fmaf(f[0], mk[u], acc[0]);  acc[1] = fmaf(f[1], mk[u], acc[1]);
            acc[2] = fmaf(f[2], mk[u], acc[2]);  acc[3] = fmaf(f[3], mk[u], acc[3]);
            dec4(r[u].y, f);
            acc[4] = fmaf(f[0], mk[u], acc[4]);  acc[5] = fmaf(f[1], mk[u], acc[5]);
            acc[6] = fmaf(f[2], mk[u], acc[6]);  acc[7] = fmaf(f[3], mk[u], acc[7]);
            dec4(r[u].z, f);
            acc[8] = fmaf(f[0], mk[u], acc[8]);  acc[9] = fmaf(f[1], mk[u], acc[9]);
            acc[10] = fmaf(f[2], mk[u], acc[10]); acc[11] = fmaf(f[3], mk[u], acc[11]);
            dec4(r[u].w, f);
            acc[12] = fmaf(f[0], mk[u], acc[12]); acc[13] = fmaf(f[1], mk[u], acc[13]);
            acc[14] = fmaf(f[2], mk[u], acc[14]); acc[15] = fmaf(f[3], mk[u], acc[15]);
        }
    }
    int ng = b * 32 + nl;
    float inv = 1.0f / (float)max(ne2 - nb, 1);
    uint4 o1, o2;
    o1.x = pack2(acc[0] * inv, acc[1] * inv);
    o1.y = pack2(acc[2] * inv, acc[3] * inv);
    o1.z = pack2(acc[4] * inv, acc[5] * inv);
    o1.w = pack2(acc[6] * inv, acc[7] * inv);
    o2.x = pack2(acc[8] * inv, acc[9] * inv);
    o2.y = pack2(acc[10] * inv, acc[11] * inv);
    o2.z = pack2(acc[12] * inv, acc[13] * inv);
    o2.w = pack2(acc[14] * inv, acc[15] * inv);
    *(uint4*)(Amean + (size_t)ng * 128 + l8 * 16) = o1;
    *(uint4*)(Amean + (size_t)ng * 128 + l8 * 16 + 8) = o2;
}

// ---- GEMM v3: ALL operands staged via global_load_lds DMA (un-sinkable, 0 VGPR cost) ----
// Round-7 counters showed VGPR=120: the compiler sank the register A-prefetch into the
// compute loop -> 8 loads in flight -> 1.24 TB/s Little's-law ceiling -> 42us.
// Now: BM=32 rows/block, grid 3125 (exact). LDS = B 64KB + A 16KB = 80KB (2 blocks/CU
// = 160KB exact). 20 DMA issues/thread = 80KB/block in flight at once.
// A is XOR-swizzled via the SOURCE address (rule: linear dest + inv-swz source + swz read)
// to kill the 16-way row-stride bank conflict on ds_read_b128.
__global__ __launch_bounds__(256, 2) void gemm_kernel(const unsigned short* __restrict__ Amean,
                                                      const void* __restrict__ x,
                                                      const unsigned short* __restrict__ xb,
                                                      const unsigned short* __restrict__ Bfrag_g,
                                                      const void* __restrict__ b_l,
                                                      unsigned int* __restrict__ Hu,
                                                      float* __restrict__ gz) {
    __shared__ unsigned short lds[40960];   // [0..32768): B  [32768..40960): A (swizzled)
    int isf32 = detect_isf32(x);
    const unsigned short* xs = isf32 ? xb : (const unsigned short*)x;
    int tid = threadIdx.x;
    int wave = tid >> 6, lane = tid & 63;
    int lm = lane & 15, lq = lane >> 4;
    int blk = blockIdx.x;
    int row0 = blk * 32;

    // -- B -> LDS linear (4096 x 16B chunks) --
    #pragma unroll
    for (int k = 0; k < 16; k++) {
        int e = tid + k * 256;
        gload_lds16(Bfrag_g + (size_t)e * 8, lds + (size_t)e * 8);
    }
    // -- A -> LDS (1024 chunks): dest linear, source inverse-XOR-swizzled --
    // dest chunk La = r*32 + csw ; source chunk c = csw ^ (r&7); c<16 -> Amean, else xb
    #pragma unroll
    for (int k = 0; k < 4; k++) {
        int La = tid + k * 256;
        int r = La >> 5, csw = La & 31;
        int c = csw ^ (r & 7);
        const unsigned short* src = (c < 16)
            ? Amean + (size_t)(row0 + r) * 128 + c * 8
            : xs + (size_t)(row0 + r) * 128 + (c - 16) * 8;
        gload_lds16(src, lds + 32768 + (size_t)La * 8);
    }

    int wc = wave & 1, wr = wave >> 1;      // wr: row-tile 0/1; wc: column half 0/1
    float bv[4];
    #pragma unroll
    for (int t = 0; t < 4; t++) bv[t] = loadS(b_l, (wc * 4 + t) * 16 + lm, isf32);

    __syncthreads();   // vmcnt drain: B + A fully in LDS (80KB was in flight at once)

    int rowl = wr * 16 + lm;                // local A row this lane consumes
    f32x4 acc[4];
    #pragma unroll
    for (int t = 0; t < 4; t++) acc[t] = (f32x4){0.f, 0.f, 0.f, 0.f};
    #pragma unroll
    for (int s = 0; s < 8; s++) {
        // swizzled A read: chunk = s*4+lq, XOR with (rowl&7) -> conflict-free b128
        bf16x8 a = *(const bf16x8*)(lds + 32768 +
                        ((size_t)rowl * 32 + (((s << 2) | lq) ^ (rowl & 7))) * 8);
        #pragma unroll
        for (int t = 0; t < 4; t++) {
            int th = wc * 4 + t;
            bf16x8 bb = *(const bf16x8*)(lds + ((th * 8 + s) * 64 + lane) * 8);
            acc[t] = __builtin_amdgcn_mfma_f32_16x16x32_bf16(a, bb, acc[t], 0, 0, 0);
        }
    }
    // -- epilogue: bias + BN partials (f32) + bf16 H store (rows exact, no bounds) --
    float st1[4], st2[4];
    int ro0 = row0 + wr * 16 + lq * 4;
    #pragma unroll
    for (int t = 0; t < 4; t++) {
        int th = wc * 4 + t;
        st1[t] = 0.f; st2[t] = 0.f;
        #pragma unroll
        for (int r = 0; r < 4; r++) {
            int ro = ro0 + r;
            float v = acc[t][r] + bv[t];
            float p = __shfl_xor(v, 1, 64);
            st1[t] += v; st2[t] += v * v;
            if (!(lm & 1)) Hu[(size_t)ro * 64 + th * 8 + (lm >> 1)] = pack2(v, p);
        }
    }
    // -- stats: reuse dead A region as sstat; merge to 1-of-8 replicated global buffers --
    __syncthreads();                         // all A reads complete
    float* sstat = (float*)(lds + 32768);    // 256 floats
    if (tid < 128) { sstat[tid] = 0.f; sstat[128 + tid] = 0.f; }
    __syncthreads();
    #pragma unroll
    for (int t = 0; t < 4; t++) {
        int col = (wc * 4 + t) * 16 + lm;
        atomicAdd(&sstat[col], st1[t]);
        atomicAdd(&sstat[128 + col], st2[t]);
    }
    __syncthreads();
    float* gzr = gz + (size_t)(blk & 7) * 256;   // replica: ~390 adds/address
    if (tid < 128) {
        atomicAdd(&gzr[tid], sstat[tid]);
        atomicAdd(&gzr[128 + tid], sstat[128 + tid]);
    }
}

// ---- normalize + LeakyReLU, 8 elems/thread; H is always bf16; stats = sum of 8 replicas ----
__global__ __launch_bounds__(256) void bn_norm_kernel(const unsigned int* __restrict__ Hu,
                                                      const void* x,
                                                      const float* gz, const void* gamma,
                                                      const void* beta, void* out) {
    __shared__ float sc[128], sh[128];
    int isf32 = detect_isf32(x);
    int tid = threadIdx.x;
    if (tid < 128) {
        float s1 = 0.f, s2 = 0.f;
        #pragma unroll
        for (int i = 0; i < 8; i++) {
            s1 += gz[i * 256 + tid];
            s2 += gz[i * 256 + 128 + tid];
        }
        const float invN = 1.0f / (float)N_NODES;
        float mu = s1 * invN;
        float var = s2 * invN - mu * mu;
        float rstd = rsqrtf(var + BN_EPS);
        float g = loadS(gamma, tid, isf32);
        float b = loadS(beta, tid, isf32);
        sc[tid] = g * rstd;
        sh[tid] = b - mu * g * rstd;
    }
    __syncthreads();
    size_t idx = (size_t)blockIdx.x * 256 + tid;
    size_t i8 = idx * 8;
    float h[8];
    {
        uint4 u = *(const uint4*)(Hu + idx * 4);
        h[0]=bflo(u.x); h[1]=bfhi(u.x); h[2]=bflo(u.y); h[3]=bfhi(u.y);
        h[4]=bflo(u.z); h[5]=bfhi(u.z); h[6]=bflo(u.w); h[7]=bfhi(u.w);
    }
    int c0 = (int)(i8 & 127);
    float o[8];
    #pragma unroll
    for (int i = 0; i < 8; i++) {
        float v = h[i] * sc[c0 + i] + sh[c0 + i];
        o[i] = (v >= 0.f) ? v : ALPHA * v;
    }
    if (isf32) {
        *(float4*)((float*)out + i8) = make_float4(o[0], o[1], o[2], o[3]);
        *(float4*)((float*)out + i8 + 4) = make_float4(o[4], o[5], o[6], o[7]);
    } else {
        uint4 u;
        u.x = pack2(o[0], o[1]); u.y = pack2(o[2], o[3]);
        u.z = pack2(o[4], o[5]); u.w = pack2(o[6], o[7]);
        *(uint4*)((unsigned short*)out + i8) = u;
    }
}

extern "C" void kernel_launch(void* const* d_in, const int* in_sizes, int n_in,
                              void* d_out, int out_size, void* d_ws, size_t ws_size,
                              hipStream_t stream) {
    const void* x     = d_in[0];
    const void* eidx  = d_in[1];
    const void* W_l   = d_in[2];
    const void* b_l   = d_in[3];
    const void* W_r   = d_in[4];
    const void* gamma = d_in[5];
    const void* beta  = d_in[6];
    char* ws = (char*)d_ws;
    float* gz = (float*)(ws + OFF_SUM);          // 8 x (gsum(128) || gsumsq(128))
    int* bT = (int*)(ws + OFF_BT);
    unsigned short* bfrag = (unsigned short*)(ws + OFF_BFRAG);
    unsigned short* Amean = (unsigned short*)(ws + OFF_AMEAN);
    unsigned int* x8 = (unsigned int*)(ws + OFF_X8);
    unsigned int* H = (unsigned int*)(ws + OFF_H);
    unsigned short* xb = (unsigned short*)(ws + OFF_XB);
    int* ghist = (int*)(ws + OFF_GHIST);         // overlays H region (dead until gemm)
    int* sOffT = (int*)(ws + OFF_SOFFT);         // overlays H region (dead until gemm)
    unsigned int* tmp = (unsigned int*)(ws + OFF_TMP2);   // overlays H region (dead until gemm)

    k1_kernel<<<NBLK_P + 3125 + 128, 256, 0, stream>>>(eidx, x, ghist, x8, xb, gz, W_l, W_r, bfrag);
    p2a_kernel<<<49, 512, 0, stream>>>(ghist, sOffT, bT);
    p3_kernel<<<NBLK_P, 1024, 0, stream>>>(eidx, sOffT, tmp);
    agg_kernel<<<NBUCK, 256, 0, stream>>>(x8, tmp, bT, Amean);
    gemm_kernel<<<GEMM_GRID, 256, 0, stream>>>(Amean, x, xb, bfrag, b_l, H, gz);
    bn_norm_kernel<<<6250, 256, 0, stream>>>(H, x, gz, gamma, beta, d_out);
}

// Round 10
// 228.685 us; speedup vs baseline: 1.0941x; 1.0941x over previous
//
#include <hip/hip_runtime.h>
#include <hip/hip_bf16.h>
#include <stdint.h>

#define N_NODES 100000
#define N_EDGES 1600000
#define DIM     128
#define ALPHA   0.01f
#define BN_EPS  1e-5f
#define NBUCK   3125          // 100000/32 buckets of 32 dst nodes (exact)
#define NBLK_P  256           // partition blocks (full chip for p3)
#define EPB     6250          // edges per partition block (256*6250 = 1.6M exact)
#define SRT_CAP 1536          // LDS sort capacity (>= BCKT_CAP)
#define BCKT_CAP 1024         // static per-bucket slot in tmp (avg 512, sigma ~23: +22s safe)
#define GEMM_GRID 391         // ceil(100000/256) one-shot blocks (2/CU cap)

typedef __bf16 bf16x8 __attribute__((ext_vector_type(8)));
typedef float  f32x4  __attribute__((ext_vector_type(4)));
typedef float  f32x2  __attribute__((ext_vector_type(2)));

#if defined(__has_builtin)
#if __has_builtin(__builtin_amdgcn_cvt_pk_fp8_f32) && __has_builtin(__builtin_amdgcn_cvt_pk_f32_fp8)
#define USE_FP8_BUILTIN 1
#endif
#endif

// ---- workspace layout (bytes) ----
static const size_t OFF_SUM   = 512;         // 128 f32 gsum + 128 f32 gsumsq (contiguous)
static const size_t OFF_BT    = 14592;       // 3125 ints: per-bucket edge counts
static const size_t OFF_BFRAG = 6432768;     // 64 KiB (end 6498304)
static const size_t OFF_AMEAN = 6498304;     // 100000x128 bf16 (end 32098304)
static const size_t OFF_X8    = 32098304;    // 100000x128 fp8 (end 44898304)
static const size_t OFF_H     = 44898304;    // 100000x128 bf16 (end 70498304)
// H region is dead until gemm -> overlay the transient buffers (stream-ordered):
static const size_t OFF_GHIST = OFF_H;                    // 256*3125 ints = 3.2 MB
static const size_t OFF_SOFFT = OFF_H + 4194304;          // 256*3125 ints = 3.2 MB
static const size_t OFF_TMP2  = OFF_H + 8388608;          // 3125*1024 u32 = 12.8 MB (ends OFF_H+21.2MB < +25.6MB)
static const size_t OFF_XB    = 70498304;    // 100000x128 bf16 x-copy (end 96098304)

__device__ __forceinline__ float bf2f(unsigned short h) {
    return __uint_as_float(((unsigned int)h) << 16);
}
__device__ __forceinline__ float bflo(unsigned int w) {
    return __uint_as_float(w << 16);
}
__device__ __forceinline__ float bfhi(unsigned int w) {
    return __uint_as_float(w & 0xffff0000u);
}
__device__ __forceinline__ unsigned short f2bf(float f) {
    unsigned int u = __float_as_uint(f);
    u = u + 0x7fffu + ((u >> 16) & 1u);   // round-to-nearest-even
    return (unsigned short)(u >> 16);
}
__device__ __forceinline__ unsigned int pack2(float a, float b) {
    return (unsigned int)f2bf(a) | ((unsigned int)f2bf(b) << 16);
}
__device__ __forceinline__ float loadS(const void* p, int i, int isf32) {
    return isf32 ? ((const float*)p)[i] : bf2f(((const unsigned short*)p)[i]);
}
__device__ __forceinline__ int edge_at(const void* e, long long i, int idx64) {
    return idx64 ? (int)((const long long*)e)[i] : ((const int*)e)[i];
}
// per-bucket chunk position of partition block k: group by (k&7) = likely XCD,
// so chunks sharing cache lines come from ONE XCD's L2 and can merge.
__device__ __forceinline__ int blkpos(int k) { return ((k & 7) << 5) | (k >> 3); }
// inverse: source block for chunk position p  (posblk(c*32+i) == i*8+c)
__device__ __forceinline__ int posblk(int p) { return ((p & 31) << 3) | (p >> 5); }

// CK-style global->LDS direct copy, 16B per lane (dest must be linear in lane order)
__device__ __forceinline__ void gload_lds16(const void* g, void* l) {
    __builtin_amdgcn_global_load_lds(
        reinterpret_cast<const __attribute__((address_space(1))) unsigned int*>(
            reinterpret_cast<uintptr_t>(g)),
        reinterpret_cast<__attribute__((address_space(3))) unsigned int*>(
            reinterpret_cast<uintptr_t>(l)),
        16, 0, 0);
}

// ---- fp8 e4m3 encode/decode ----
#ifndef USE_FP8_BUILTIN
__device__ __forceinline__ unsigned int enc_fp8_1(float f) {
    unsigned int u = __float_as_uint(f);
    unsigned int s = (u >> 24) & 0x80u;
    unsigned int au = u & 0x7fffffffu;
    if (au >= 0x43E00000u) return s | 0x7Eu;               // clamp to 448
    if (au < 0x3C800000u) {                                 // subnormal / zero
        int m = (int)rintf(__uint_as_float(au) * 512.0f);
        return s | (unsigned int)m;
    }
    unsigned int r = au + 0x7FFFFu + ((au >> 20) & 1u);     // RNE to 3 mantissa bits
    unsigned int e = (r >> 23) & 0xffu;
    unsigned int m3 = (r >> 20) & 7u;
    return s | ((e - 120u) << 3) | m3;
}
#endif
__device__ __forceinline__ unsigned int enc4(float f0, float f1, float f2, float f3) {
#ifdef USE_FP8_BUILTIN
    int r = __builtin_amdgcn_cvt_pk_fp8_f32(f0, f1, 0, false);
    r = __builtin_amdgcn_cvt_pk_fp8_f32(f2, f3, r, true);
    return (unsigned int)r;
#else
    return enc_fp8_1(f0) | (enc_fp8_1(f1) << 8) | (enc_fp8_1(f2) << 16) | (enc_fp8_1(f3) << 24);
#endif
}
__device__ __forceinline__ void dec4(unsigned int w, float* o) {
#ifdef USE_FP8_BUILTIN
    f32x2 a = __builtin_amdgcn_cvt_pk_f32_fp8(w, false);
    f32x2 b = __builtin_amdgcn_cvt_pk_f32_fp8(w, true);
    o[0] = a[0]; o[1] = a[1]; o[2] = b[0]; o[3] = b[1];
#else
    #pragma unroll
    for (int j = 0; j < 4; j++) {
        unsigned int c = (w >> (8 * j)) & 0xffu;
        o[j] = __uint_as_float(((c & 0x80u) << 24) | ((c & 0x7fu) << 20)) * 0x1p120f;
    }
#endif
}

// ---- wave-uniform dtype detection ----
__device__ __forceinline__ int detect_idx64(const void* e) {
    const unsigned int* ew = (const unsigned int*)e;
    unsigned long long m = __ballot(ew[2 * (threadIdx.x & 63) + 1] != 0u);
    return (__popcll(m) < 8) ? 1 : 0;
}
__device__ __forceinline__ int detect_isf32(const void* x) {
    const unsigned int* xw = (const unsigned int*)x;
    unsigned int w = xw[threadIdx.x & 63];
    unsigned int e = (w >> 7) & 0xffu;
    bool bflike = (e >= 110u && e <= 140u) || ((w & 0xffffu) == 0u);
    unsigned long long m = __ballot(bflike);
    return (__popcll(m) > 32) ? 0 : 1;
}

// ---- k1: hist (blocks 0..255, block 0 zeros BN stats) + x->fp8(+bf16) (3125 blocks)
//      + B-fragment swizzle prep (last 128 blocks) ----
__global__ __launch_bounds__(256) void k1_kernel(const void* edges, const void* x,
                                                 int* ghist, unsigned int* x8,
                                                 unsigned short* xb, float* gz,
                                                 const void* W_l, const void* W_r,
                                                 unsigned short* bfrag) {
    int tid = threadIdx.x;
    if (blockIdx.x < NBLK_P) {
        __shared__ int sh[NBUCK];
        int idx64 = detect_idx64(edges);
        int blk = blockIdx.x;
        if (blk == 0) gz[tid] = 0.f;   // 256 floats: gsum+gsumsq
        for (int i = tid; i < NBUCK; i += 256) sh[i] = 0;
        __syncthreads();
        long long base = (long long)blk * EPB;
        for (int i = tid; i < EPB; i += 256) {
            int d = edge_at(edges, (long long)N_EDGES + base + i, idx64);
            atomicAdd(&sh[d >> 5], 1);
        }
        __syncthreads();
        for (int i = tid; i < NBUCK; i += 256) ghist[blk * NBUCK + i] = sh[i];
    } else if (blockIdx.x < NBLK_P + 3125) {
        int isf32 = detect_isf32(x);
        int gid = (blockIdx.x - NBLK_P) * 256 + tid;
        float f[16];
        if (!isf32) {
            const uint4* xv = (const uint4*)x;
            uint4 a = xv[gid * 2], b2 = xv[gid * 2 + 1];
            unsigned int w[8] = {a.x, a.y, a.z, a.w, b2.x, b2.y, b2.z, b2.w};
            #pragma unroll
            for (int i = 0; i < 8; i++) { f[2 * i] = bflo(w[i]); f[2 * i + 1] = bfhi(w[i]); }
        } else {
            const float4* xf = (const float4*)x;
            #pragma unroll
            for (int i = 0; i < 4; i++) {
                float4 v = xf[gid * 4 + i];
                f[4 * i] = v.x; f[4 * i + 1] = v.y; f[4 * i + 2] = v.z; f[4 * i + 3] = v.w;
            }
            // bf16 copy of x for the gemm A-side (halves its fetch, kills f2bf there)
            uint4 h1, h2;
            h1.x = pack2(f[0], f[1]);  h1.y = pack2(f[2], f[3]);
            h1.z = pack2(f[4], f[5]);  h1.w = pack2(f[6], f[7]);
            h2.x = pack2(f[8], f[9]);  h2.y = pack2(f[10], f[11]);
            h2.z = pack2(f[12], f[13]); h2.w = pack2(f[14], f[15]);
            ((uint4*)xb)[gid * 2]     = h1;
            ((uint4*)xb)[gid * 2 + 1] = h2;
        }
        uint4 o;
        o.x = enc4(f[0], f[1], f[2], f[3]);
        o.y = enc4(f[4], f[5], f[6], f[7]);
        o.z = enc4(f[8], f[9], f[10], f[11]);
        o.w = enc4(f[12], f[13], f[14], f[15]);
        *(uint4*)(x8 + gid * 4) = o;
    } else {
        // B-fragment swizzle: 128 blocks x 256 = 32768 elems
        int isf32 = detect_isf32(x);
        int g = (blockIdx.x - NBLK_P - 3125) * 256 + tid;
        int j    = g & 7;
        int lane = (g >> 3) & 63;
        int s    = (g >> 9) & 7;
        int tt   = (g >> 12) & 7;
        int n = tt * 16 + (lane & 15);
        int k = s * 32 + ((lane >> 4) & 3) * 8 + j;
        float v = (k < DIM) ? loadS(W_l, n * DIM + k, isf32)
                            : loadS(W_r, n * DIM + (k - DIM), isf32);
        bfrag[g] = f2bf(v);
    }
}

// ---- p2a: per-bucket scan, 8-way parallel over position-chunks ----
__global__ __launch_bounds__(512) void p2a_kernel(const int* __restrict__ ghist,
                                                  int* __restrict__ sOffT,
                                                  int* __restrict__ bT) {
    __shared__ int csum[8][64];
    int t = threadIdx.x;
    int c = t >> 6, bl = t & 63;
    int b = blockIdx.x * 64 + bl;
    int v[32]; int s = 0;
    if (b < NBUCK) {
        #pragma unroll
        for (int i = 0; i < 32; i++) { v[i] = ghist[(size_t)(i * 8 + c) * NBUCK + b]; s += v[i]; }
    }
    csum[c][bl] = s;
    __syncthreads();
    if (b < NBUCK) {
        int run = 0;
        for (int i = 0; i < c; i++) run += csum[i][bl];
        #pragma unroll
        for (int i = 0; i < 32; i++) { sOffT[(size_t)(c * 32 + i) * NBUCK + b] = run; run += v[i]; }
        if (c == 7) bT[b] = run;
    }
}

// ---- p3: scatter edges into STATIC bucket slots (bucket b occupies tmp[b<<10 ..]) ----
__global__ __launch_bounds__(1024) void p3_kernel(const void* edges, const int* __restrict__ sOffT,
                                                  unsigned int* __restrict__ tmp) {
    __shared__ int sbase[NBUCK];
    int idx64 = detect_idx64(edges);
    int blk = blockIdx.x, tid = threadIdx.x;
    int mypos = blkpos(blk);
    for (int i = tid; i < NBUCK; i += 1024)
        sbase[i] = (i << 10) + sOffT[(size_t)mypos * NBUCK + i];   // static slot + coalesced offset
    __syncthreads();
    long long base = (long long)blk * EPB;
    for (int i = tid; i < EPB; i += 1024) {
        long long e = base + i;
        int s = edge_at(edges, e, idx64);
        int d = edge_at(edges, (long long)N_EDGES + e, idx64);
        int bkt = d >> 5;
        int p = atomicAdd(&sbase[bkt], 1);
        if (p < ((bkt + 1) << 10))                      // slot-overflow clamp (+22 sigma, never fires)
            tmp[p] = ((unsigned int)(d & 31) << 17) | (unsigned int)s;
    }
}

// ---- aggregation: LDS counting sort, then oct-per-node gather (no cross-lane reduce) ----
__global__ __launch_bounds__(256) void agg_kernel(const unsigned int* x8, const unsigned int* tmp,
                                                  const int* __restrict__ bT, unsigned short* Amean) {
    __shared__ int s_cnt[32];
    __shared__ int s_beg[32];
    __shared__ int s_srt[SRT_CAP];
    int b = blockIdx.x, tid = threadIdx.x;
    int gb = b << 10;                       // static slot base
    int nE = min(bT[b], BCKT_CAP);
    if (tid < 32) s_cnt[tid] = 0;
    __syncthreads();
    for (int i = tid; i < nE; i += 256) atomicAdd(&s_cnt[tmp[gb + i] >> 17], 1);
    __syncthreads();
    if (tid < 32) {
        int v = s_cnt[tid];
        int sc = v;
        #pragma unroll
        for (int off = 1; off < 32; off <<= 1) {
            int u = __shfl_up(sc, off, 64);
            if (tid >= off) sc += u;
        }
        s_beg[tid] = sc - v;
        s_cnt[tid] = sc - v;    // reuse as write ptr
    }
    __syncthreads();
    for (int i = tid; i < nE; i += 256) {
        unsigned int w = tmp[gb + i];
        int p = atomicAdd(&s_cnt[w >> 17], 1);
        s_srt[p] = (int)(w & 0x1ffffu);
    }
    __syncthreads();
    // each 8-lane oct owns ONE node: no cross-lane reduction needed.
    int wv = tid >> 6, lane = tid & 63;
    int oct = lane >> 3, l8 = lane & 7;
    int nl = wv * 8 + oct;                  // node 0..31 within bucket
    int nb = s_beg[nl], ne2 = s_cnt[nl];
    const uint4* xv = (const uint4*)x8;     // fp8 row = 8 uint4
    float acc[16];
    #pragma unroll
    for (int i = 0; i < 16; i++) acc[i] = 0.f;
    for (int jj = nb; jj < ne2; jj += 4) {
        uint4 r[4]; float mk[4];
        #pragma unroll
        for (int u = 0; u < 4; u++) {
            int e = jj + u;
            int su = s_srt[(e < ne2) ? e : nb];   // LDS broadcast across the oct
            mk[u] = (e < ne2) ? 1.f : 0.f;
            r[u] = xv[(size_t)su * 8 + l8];
        }
        #pragma unroll
        for (int u = 0; u < 4; u++) {
            float f[4];
            dec4(r[u].x, f);
            acc[0] = fmaf(f[0], mk[u], acc[0]);  acc[1] = fmaf(f[1], mk[u], acc[1]);
            acc[2] = fmaf(f[2], mk[u], acc[2]);  acc[3] = fmaf(f[3], mk[u], acc[3]);
            dec4(r[u].y, f);
            acc[4] = fmaf(f[0], mk[u], acc[4]);  acc[5] = fmaf(f[1], mk[u], acc[5]);
            acc[6] = fmaf(f[2], mk[u], acc[6]);  acc[7] = fmaf(f[3], mk[u], acc[7]);
            dec4(r[u].z, f);
            acc[8] = fmaf(f[0], mk[u], acc[8]);  acc[9] = fmaf(f[1], mk[u], acc[9]);
            acc[10] = fmaf(f[2], mk[u], acc[10]); acc[11] = fmaf(f[3], mk[u], acc[11]);
            dec4(r[u].w, f);
            acc[12] = fmaf(f[0], mk[u], acc[12]); acc[13] = fmaf(f[1], mk[u], acc[13]);
            acc[14] = fmaf(f[2], mk[u], acc[14]); acc[15] = fmaf(f[3], mk[u], acc[15]);
        }
    }
    int ng = b * 32 + nl;
    float inv = 1.0f / (float)max(ne2 - nb, 1);
    uint4 o1, o2;
    o1.x = pack2(acc[0] * inv, acc[1] * inv);
    o1.y = pack2(acc[2] * inv, acc[3] * inv);
    o1.z = pack2(acc[4] * inv, acc[5] * inv);
    o1.w = pack2(acc[6] * inv, acc[7] * inv);
    o2.x = pack2(acc[8] * inv, acc[9] * inv);
    o2.y = pack2(acc[10] * inv, acc[11] * inv);
    o2.z = pack2(acc[12] * inv, acc[13] * inv);
    o2.w = pack2(acc[14] * inv, acc[15] * inv);
    *(uint4*)(Amean + (size_t)ng * 128 + l8 * 16) = o1;
    *(uint4*)(Amean + (size_t)ng * 128 + l8 * 16 + 8) = o2;
}

// ---- one-shot MFMA GEMM + fused BN stats; H stored bf16 ----
// Round-7 regression root-cause: the compiler SANK the register A-prefetch into the
// per-tile compute loop (VGPR 192->120), collapsing in-flight bytes to 8 loads/wave
// -> 1.24 TB/s Little's-law ceiling -> 42us. Round-8's BM=32 DMA variant fixed MLP
// but lost 8x amortization (B reloaded 3125x, 61us). This version: round-7 structure
// + __builtin_amdgcn_sched_barrier(0) pinning ALL 32 A-loads above the barrier
// (the machine scheduler may not move instructions across it — rule #18 fence).
// In-flight per block: 64KB B-DMA + 128KB A-regs. Tell: VGPR_Count >= ~180.
__global__ __launch_bounds__(256, 2) void gemm_kernel(const unsigned short* __restrict__ Amean,
                                                      const void* __restrict__ x,
                                                      const unsigned short* __restrict__ xb,
                                                      const unsigned short* __restrict__ Bfrag_g,
                                                      const void* __restrict__ b_l,
                                                      unsigned int* __restrict__ Hu,
                                                      float* __restrict__ gz) {
    __shared__ unsigned short lds[32768];
    __shared__ float sstat[2][128];
    int isf32 = detect_isf32(x);
    const unsigned short* xs = isf32 ? xb : (const unsigned short*)x;
    int tid = threadIdx.x;
    int wave = tid >> 6, lane = tid & 63;
    int lm = lane & 15, lq = lane >> 4;

    // -- B -> LDS, direct (linear dest: element e = tid + k*256, 16B each) --
    #pragma unroll
    for (int k = 0; k < 16; k++) {
        int e = tid + k * 256;
        gload_lds16(Bfrag_g + (size_t)e * 8, lds + (size_t)e * 8);
    }
    if (tid < 128) { sstat[0][tid] = 0.f; sstat[1][tid] = 0.f; }

    // -- all A fragments for this block's 256 rows (4 tiles per wave) --
    int base = blockIdx.x * 256;
    bf16x8 aq[4][8];
    #pragma unroll
    for (int j = 0; j < 4; j++) {
        int rowA = base + (wave * 4 + j) * 16 + lm;
        if (rowA >= N_NODES) rowA = N_NODES - 1;
        const unsigned short* am = Amean + (size_t)rowA * 128 + lq * 8;
        const unsigned short* xm = xs + (size_t)rowA * 128 + lq * 8;
        #pragma unroll
        for (int s = 0; s < 4; s++) aq[j][s] = *(const bf16x8*)(am + s * 32);
        #pragma unroll
        for (int s = 0; s < 4; s++) aq[j][4 + s] = *(const bf16x8*)(xm + s * 32);
    }
    // PIN: no instruction (incl. the 32 A-loads above) may be scheduled across this
    // point. Prevents the round-7 sink that serialized the loads into the MFMA loop.
    __builtin_amdgcn_sched_barrier(0);

    float bv[8];
    #pragma unroll
    for (int t = 0; t < 8; t++) bv[t] = loadS(b_l, t * 16 + lm, isf32);
    float st1[8], st2[8];
    #pragma unroll
    for (int t = 0; t < 8; t++) { st1[t] = 0.f; st2[t] = 0.f; }

    __syncthreads();   // drains vmcnt: B in LDS, A in regs, all loads were in flight together

    #pragma unroll
    for (int j = 0; j < 4; j++) {
        f32x4 acc[8];
        #pragma unroll
        for (int t = 0; t < 8; t++) acc[t] = (f32x4){0.f, 0.f, 0.f, 0.f};
        #pragma unroll
        for (int s = 0; s < 8; s++) {
            #pragma unroll
            for (int t = 0; t < 8; t++) {
                bf16x8 bb = *(const bf16x8*)(lds + ((t * 8 + s) * 64 + lane) * 8);
                acc[t] = __builtin_amdgcn_mfma_f32_16x16x32_bf16(aq[j][s], bb, acc[t], 0, 0, 0);
            }
        }
        // epilogue tile j: BN stats (f32) + bf16 H store (overlaps next tile's MFMA)
        #pragma unroll
        for (int t = 0; t < 8; t++) {
            #pragma unroll
            for (int r = 0; r < 4; r++) {
                int ro = base + (wave * 4 + j) * 16 + lq * 4 + r;
                float v = acc[t][r] + bv[t];
                float p = __shfl_xor(v, 1, 64);
                bool in = (ro < N_NODES);
                if (in) { st1[t] += v; st2[t] += v * v; }
                if (in && !(lm & 1)) Hu[(size_t)ro * 64 + t * 8 + (lm >> 1)] = pack2(v, p);
            }
        }
    }
    #pragma unroll
    for (int t = 0; t < 8; t++) {
        atomicAdd(&sstat[0][t * 16 + lm], st1[t]);
        atomicAdd(&sstat[1][t * 16 + lm], st2[t]);
    }
    __syncthreads();
    if (tid < 128) {
        atomicAdd(&gz[tid], sstat[0][tid]);          // gsum
        atomicAdd(&gz[128 + tid], sstat[1][tid]);    // gsumsq
    }
}

// ---- normalize + LeakyReLU, 8 elems/thread; H is always bf16 ----
__global__ __launch_bounds__(256) void bn_norm_kernel(const unsigned int* __restrict__ Hu,
                                                      const void* x,
                                                      const float* gsum,
                                                      const float* gsumsq, const void* gamma,
                                                      const void* beta, void* out) {
    __shared__ float sc[128], sh[128];
    int isf32 = detect_isf32(x);
    int tid = threadIdx.x;
    if (tid < 128) {
        const float invN = 1.0f / (float)N_NODES;
        float mu = gsum[tid] * invN;
        float var = gsumsq[tid] * invN - mu * mu;
        float rstd = rsqrtf(var + BN_EPS);
        float g = loadS(gamma, tid, isf32);
        float b = loadS(beta, tid, isf32);
        sc[tid] = g * rstd;
        sh[tid] = b - mu * g * rstd;
    }
    __syncthreads();
    size_t idx = (size_t)blockIdx.x * 256 + tid;
    size_t i8 = idx * 8;
    float h[8];
    {
        uint4 u = *(const uint4*)(Hu + idx * 4);
        h[0]=bflo(u.x); h[1]=bfhi(u.x); h[2]=bflo(u.y); h[3]=bfhi(u.y);
        h[4]=bflo(u.z); h[5]=bfhi(u.z); h[6]=bflo(u.w); h[7]=bfhi(u.w);
    }
    int c0 = (int)(i8 & 127);
    float o[8];
    #pragma unroll
    for (int i = 0; i < 8; i++) {
        float v = h[i] * sc[c0 + i] + sh[c0 + i];
        o[i] = (v >= 0.f) ? v : ALPHA * v;
    }
    if (isf32) {
        *(float4*)((float*)out + i8) = make_float4(o[0], o[1], o[2], o[3]);
        *(float4*)((float*)out + i8 + 4) = make_float4(o[4], o[5], o[6], o[7]);
    } else {
        uint4 u;
        u.x = pack2(o[0], o[1]); u.y = pack2(o[2], o[3]);
        u.z = pack2(o[4], o[5]); u.w = pack2(o[6], o[7]);
        *(uint4*)((unsigned short*)out + i8) = u;
    }
}

extern "C" void kernel_launch(void* const* d_in, const int* in_sizes, int n_in,
                              void* d_out, int out_size, void* d_ws, size_t ws_size,
                              hipStream_t stream) {
    const void* x     = d_in[0];
    const void* eidx  = d_in[1];
    const void* W_l   = d_in[2];
    const void* b_l   = d_in[3];
    const void* W_r   = d_in[4];
    const void* gamma = d_in[5];
    const void* beta  = d_in[6];
    char* ws = (char*)d_ws;
    float* gz = (float*)(ws + OFF_SUM);          // gsum(128) || gsumsq(128)
    int* bT = (int*)(ws + OFF_BT);
    unsigned short* bfrag = (unsigned short*)(ws + OFF_BFRAG);
    unsigned short* Amean = (unsigned short*)(ws + OFF_AMEAN);
    unsigned int* x8 = (unsigned int*)(ws + OFF_X8);
    unsigned int* H = (unsigned int*)(ws + OFF_H);
    unsigned short* xb = (unsigned short*)(ws + OFF_XB);
    int* ghist = (int*)(ws + OFF_GHIST);         // overlays H region (dead until gemm)
    int* sOffT = (int*)(ws + OFF_SOFFT);         // overlays H region (dead until gemm)
    unsigned int* tmp = (unsigned int*)(ws + OFF_TMP2);   // overlays H region (dead until gemm)

    k1_kernel<<<NBLK_P + 3125 + 128, 256, 0, stream>>>(eidx, x, ghist, x8, xb, gz, W_l, W_r, bfrag);
    p2a_kernel<<<49, 512, 0, stream>>>(ghist, sOffT, bT);
    p3_kernel<<<NBLK_P, 1024, 0, stream>>>(eidx, sOffT, tmp);
    agg_kernel<<<NBUCK, 256, 0, stream>>>(x8, tmp, bT, Amean);
    gemm_kernel<<<GEMM_GRID, 256, 0, stream>>>(Amean, x, xb, bfrag, b_l, H, gz);
    bn_norm_kernel<<<6250, 256, 0, stream>>>(H, x, gz, gz + 128, gamma, beta, d_out);
}